// Round 5
// baseline (119.895 us; speedup 1.0000x reference)
//
#include <hip/hip_runtime.h>
#include <hip/hip_bf16.h>

// out[n,h] = x[n,h] * weight[h] + bias[h]
// N=16384, H=4096, fp32 in/out. Pure streaming.
// One-shot flat grid: each thread handles exactly one 32 B chunk (float8 ->
// 2x global_load_dwordx4), perfectly contiguous across the grid, no loop.
// w/b are L2-resident (16 KiB each); h8 = tid & (H/8-1) since H/8 = 512 is
// a power of two. 32768 blocks x 256 threads exactly covers N*H/8 chunks.

typedef float v8f __attribute__((ext_vector_type(8)));

__global__ __launch_bounds__(256) void scale_shift_f32_oneshot(
    const v8f* __restrict__ x,
    const v8f* __restrict__ w,
    const v8f* __restrict__ b,
    v8f* __restrict__ out,
    int total8, int h8mask) {
    const int i = blockIdx.x * blockDim.x + threadIdx.x;
    if (i < total8) {
        const int h8 = i & h8mask;
        out[i] = x[i] * w[h8] + b[h8];
    }
}

extern "C" void kernel_launch(void* const* d_in, const int* in_sizes, int n_in,
                              void* d_out, int out_size, void* d_ws, size_t ws_size,
                              hipStream_t stream) {
    const float* x = (const float*)d_in[0];
    const float* w = (const float*)d_in[1];
    const float* b = (const float*)d_in[2];
    float* out = (float*)d_out;

    const int H = in_sizes[1];           // 4096
    const int total = out_size;          // N*H = 67,108,864
    const int total8 = total / 8;        // 8,388,608 float8 chunks
    const int h8mask = H / 8 - 1;        // 511

    const int block = 256;
    const int grid = (total8 + block - 1) / block;   // 32768, exact cover

    scale_shift_f32_oneshot<<<grid, block, 0, stream>>>(
        (const v8f*)x, (const v8f*)w, (const v8f*)b,
        (v8f*)out, total8, h8mask);
}

// Round 6
// 94.739 us; speedup vs baseline: 1.2655x; 1.2655x over previous
//
#include <hip/hip_runtime.h>
#include <hip/hip_bf16.h>

// out[n,h] = x[n,h] * weight[h] + bias[h]
// N=16384, H=4096, fp32 in/out. Pure streaming.
// R4 structure (hoisted w/b, x2 unroll, normal LOADS) + non-temporal STORES
// only. Rationale: out is write-once/never-read -> nt keeps its lines out of
// L2/L3, so x (256 MiB, exactly L3-sized) can stay L3-resident across graph
// replays; normal loads are then L3 hits. R3's regression is attributed to
// the nt LOAD (bypassed L3 residency of x), to be confirmed by this A/B.

typedef float v4f __attribute__((ext_vector_type(4)));

__global__ __launch_bounds__(256) void scale_shift_f32_ntst(
    const v4f* __restrict__ x,
    const v4f* __restrict__ w,
    const v4f* __restrict__ b,
    v4f* __restrict__ out,
    int total4, int h4mask) {
    const int tid = blockIdx.x * blockDim.x + threadIdx.x;
    const int stride = gridDim.x * blockDim.x;   // host guarantees: multiple of (h4mask+1)

    const int h4 = tid & h4mask;                 // loop-invariant by construction
    const v4f wv = w[h4];
    const v4f bv = b[h4];

    int i = tid;
    for (; i + stride < total4; i += 2 * stride) {
        v4f x0 = x[i];                           // normal load: may hit L3
        v4f x1 = x[i + stride];
        v4f o0 = x0 * wv + bv;
        v4f o1 = x1 * wv + bv;
        __builtin_nontemporal_store(o0, &out[i]);            // nt store: don't pollute L2/L3
        __builtin_nontemporal_store(o1, &out[i + stride]);
    }
    for (; i < total4; i += stride) {
        v4f o = x[i] * wv + bv;
        __builtin_nontemporal_store(o, &out[i]);
    }
}

extern "C" void kernel_launch(void* const* d_in, const int* in_sizes, int n_in,
                              void* d_out, int out_size, void* d_ws, size_t ws_size,
                              hipStream_t stream) {
    const float* x = (const float*)d_in[0];
    const float* w = (const float*)d_in[1];
    const float* b = (const float*)d_in[2];
    float* out = (float*)d_out;

    const int H = in_sizes[1];           // 4096
    const int total = out_size;          // N*H = 67,108,864
    const int total4 = total / 4;
    const int h4 = H / 4;                // 1024, power of two
    const int h4mask = h4 - 1;

    const int block = 256;
    int grid = 2048;                     // 2048*256 = 524288, multiple of 1024
    while ((long long)grid * block % h4 != 0 && grid > 1) grid--;

    scale_shift_f32_ntst<<<grid, block, 0, stream>>>(
        (const v4f*)x, (const v4f*)w, (const v4f*)b,
        (v4f*)out, total4, h4mask);
}

// Round 7
// 85.084 us; speedup vs baseline: 1.4091x; 1.1135x over previous
//
#include <hip/hip_runtime.h>
#include <hip/hip_bf16.h>

// out[n,h] = x[n,h] * weight[h] + bias[h]
// N=16384, H=4096, fp32 in/out. Pure streaming.
// R6 structure (hoisted w/b, x2 unroll, normal loads) but stores via
// inline-asm global_store_dwordx4 with sc0 sc1 nt — attempting FULL cache
// bypass for the write stream so x (256 MiB == L3 size) converges to fully
// L3-resident across graph replays. R6 measured FETCH=131MB (50% x-hit),
// consistent with nt-builtin stores still allocating in L3.

typedef float v4f __attribute__((ext_vector_type(4)));

__device__ __forceinline__ void store_bypass(v4f val, v4f* addr) {
    asm volatile("global_store_dwordx4 %0, %1, off sc0 sc1 nt"
                 :: "v"(addr), "v"(val)
                 : "memory");
}

__global__ __launch_bounds__(256) void scale_shift_f32_ntbyp(
    const v4f* __restrict__ x,
    const v4f* __restrict__ w,
    const v4f* __restrict__ b,
    v4f* __restrict__ out,
    int total4, int h4mask) {
    const int tid = blockIdx.x * blockDim.x + threadIdx.x;
    const int stride = gridDim.x * blockDim.x;   // host guarantees: multiple of (h4mask+1)

    const int h4 = tid & h4mask;                 // loop-invariant by construction
    const v4f wv = w[h4];
    const v4f bv = b[h4];

    int i = tid;
    for (; i + stride < total4; i += 2 * stride) {
        v4f x0 = x[i];                           // normal load: L3 hits when resident
        v4f x1 = x[i + stride];
        v4f o0 = x0 * wv + bv;
        v4f o1 = x1 * wv + bv;
        store_bypass(o0, &out[i]);
        store_bypass(o1, &out[i + stride]);
    }
    for (; i < total4; i += stride) {
        v4f o = x[i] * wv + bv;
        store_bypass(o, &out[i]);
    }
}

extern "C" void kernel_launch(void* const* d_in, const int* in_sizes, int n_in,
                              void* d_out, int out_size, void* d_ws, size_t ws_size,
                              hipStream_t stream) {
    const float* x = (const float*)d_in[0];
    const float* w = (const float*)d_in[1];
    const float* b = (const float*)d_in[2];
    float* out = (float*)d_out;

    const int H = in_sizes[1];           // 4096
    const int total = out_size;          // N*H = 67,108,864
    const int total4 = total / 4;
    const int h4 = H / 4;                // 1024, power of two
    const int h4mask = h4 - 1;

    const int block = 256;
    int grid = 2048;                     // 2048*256 = 524288, multiple of 1024
    while ((long long)grid * block % h4 != 0 && grid > 1) grid--;

    scale_shift_f32_ntbyp<<<grid, block, 0, stream>>>(
        (const v4f*)x, (const v4f*)w, (const v4f*)b,
        (v4f*)out, total4, h4mask);
}